// Round 6
// baseline (409.658 us; speedup 1.0000x reference)
//
#include <hip/hip_runtime.h>

#define N_NODES 100000
#define DEG 16
#define DIM 128
#define E_EDGES 1600000
#define NTILES 1563          // ceil(100000/64)
#define LSTR 136             // LDS row stride in shorts (16B-aligned, conflict-light)

typedef short bf16x8 __attribute__((ext_vector_type(8)));
typedef float f32x4 __attribute__((ext_vector_type(4)));

__device__ __forceinline__ unsigned short f2bf(float f) {
    unsigned int u = __builtin_bit_cast(unsigned int, f);
    u = (u + 0x7fffu + ((u >> 16) & 1u)) >> 16;
    return (unsigned short)u;
}
__device__ __forceinline__ float bf2f(unsigned short h) {
    unsigned int u = ((unsigned int)h) << 16;
    return __builtin_bit_cast(float, u);
}
__device__ __forceinline__ bf16x8 pack_bf16x8(float4 lo, float4 hi) {
    bf16x8 f;
    f[0] = (short)f2bf(lo.x); f[1] = (short)f2bf(lo.y);
    f[2] = (short)f2bf(lo.z); f[3] = (short)f2bf(lo.w);
    f[4] = (short)f2bf(hi.x); f[5] = (short)f2bf(hi.y);
    f[6] = (short)f2bf(hi.z); f[7] = (short)f2bf(hi.w);
    return f;
}

// ---------------------------------------------------------------------------
// prep: cast W_W1|W_U1 -> Wc1 (256x128 bf16), W_W2|W_U2 -> Wc2
// ---------------------------------------------------------------------------
__global__ __launch_bounds__(256) void prep_w(
    const float* __restrict__ W_W1, const float* __restrict__ W_U1,
    const float* __restrict__ W_W2, const float* __restrict__ W_U2,
    unsigned short* __restrict__ Wc1, unsigned short* __restrict__ Wc2)
{
    int idx = blockIdx.x * 256 + threadIdx.x;      // 0..65535
    int half = idx & 32767;
    const float* src = (idx < 32768)
        ? (half < 16384 ? W_W1 + half : W_U1 + half - 16384)
        : (half < 16384 ? W_W2 + half : W_U2 + half - 16384);
    unsigned short* dst = (idx < 32768) ? Wc1 + half : Wc2 + half;
    *dst = f2bf(*src);
}

// ---------------------------------------------------------------------------
// dense_fused: one block per 64-node tile computes ALL 256 output cols
// (z 0..127 and zi 0..127). H staged once in LDS (17 KB bf16); W fragments
// read straight from global (64 KB, shared by all blocks -> L1/L2 broadcast,
// same pattern as the old fused aggr_dense phase 3). 64 MFMA/wave per stage
// (4x the old work-per-stage), attr fetched exactly once from HBM.
// ---------------------------------------------------------------------------
__global__ __launch_bounds__(256) void dense_fused(
    const float* __restrict__ hsrc,          // N x 128 f32 (attr)
    const unsigned short* __restrict__ Wc,   // 256 x 128 bf16 (W_W|W_U)
    const float* __restrict__ W_a,           // 257 f32
    unsigned short* __restrict__ z,
    unsigned short* __restrict__ zi,
    float* __restrict__ s_src0, float* __restrict__ s_src1,
    float* __restrict__ s_dst0, float* __restrict__ s_dst1)
{
    __shared__ unsigned short Ht[64 * LSTR];

    const int nodebase = blockIdx.x * 64;
    const int t = threadIdx.x;

    // ---- stage h tile: 64 nodes x 128 f32 -> bf16, once per tile ----
    {
        int r = t >> 2, c0 = (t & 3) * 32;
        int node = nodebase + r;
        unsigned short* dst = Ht + r * LSTR + c0;
        float4 v[8];
#pragma unroll
        for (int i = 0; i < 8; i++) v[i] = make_float4(0.f, 0.f, 0.f, 0.f);
        if (node < N_NODES) {
            const float* src = hsrc + (size_t)node * DIM + c0;
#pragma unroll
            for (int i = 0; i < 8; i++) v[i] = *(const float4*)(src + i * 4);
        }
#pragma unroll
        for (int i = 0; i < 4; i++)
            *(bf16x8*)(dst + i * 8) = pack_bf16x8(v[2 * i], v[2 * i + 1]);
    }
    __syncthreads();

    const int wave = t >> 6;
    const int lane = t & 63;
    const int n16 = lane & 15;
    const int quad = lane >> 4;
    const int node = nodebase + wave * 16 + n16;   // wave owns 16 nodes, all cols

    bf16x8 hfrag[4];
    const unsigned short* hrow = Ht + (wave * 16 + n16) * LSTR + quad * 8;
#pragma unroll
    for (int ks = 0; ks < 4; ks++)
        hfrag[ks] = *(const bf16x8*)(hrow + ks * 32);

#pragma unroll
    for (int cb = 0; cb < 4; cb++) {
        f32x4 acc[4];
#pragma unroll
        for (int ct = 0; ct < 4; ct++) {
            const unsigned short* wrow =
                Wc + (size_t)(cb * 64 + ct * 16 + n16) * DIM + quad * 8;
            f32x4 a = {0.f, 0.f, 0.f, 0.f};
#pragma unroll
            for (int ks = 0; ks < 4; ks++)
                a = __builtin_amdgcn_mfma_f32_16x16x32_bf16(
                        *(const bf16x8*)(wrow + ks * 32), hfrag[ks], a, 0, 0, 0);
            acc[ct] = a;
        }

        if (node < N_NODES) {
            unsigned short* zout = (cb < 2 ? z : zi);
            unsigned short* orow = zout + (size_t)node * DIM + (cb & 1) * 64 + quad * 4;
#pragma unroll
            for (int ct = 0; ct < 4; ct++) {
                uint2 pk;
                pk.x = (unsigned int)f2bf(acc[ct][0]) | ((unsigned int)f2bf(acc[ct][1]) << 16);
                pk.y = (unsigned int)f2bf(acc[ct][2]) | ((unsigned int)f2bf(acc[ct][3]) << 16);
                *(uint2*)(orow + ct * 16) = pk;
            }
        }

        if (cb < 2) {
            float ps = 0.f, pd = 0.f;
#pragma unroll
            for (int ct = 0; ct < 4; ct++) {
                float4 as = *(const float4*)(W_a + cb * 64 + ct * 16 + quad * 4);
                float4 ad = *(const float4*)(W_a + DIM + cb * 64 + ct * 16 + quad * 4);
                ps += acc[ct][0] * as.x + acc[ct][1] * as.y
                    + acc[ct][2] * as.z + acc[ct][3] * as.w;
                pd += acc[ct][0] * ad.x + acc[ct][1] * ad.y
                    + acc[ct][2] * ad.z + acc[ct][3] * ad.w;
            }
            ps += __shfl_xor(ps, 16); ps += __shfl_xor(ps, 32);
            pd += __shfl_xor(pd, 16); pd += __shfl_xor(pd, 32);
            if (lane < 16 && node < N_NODES) {
                (cb == 0 ? s_src0 : s_src1)[node] = ps;
                (cb == 0 ? s_dst0 : s_dst1)[node] = pd;
            }
        }
    }
}

// ---------------------------------------------------------------------------
// dense_fused_b: same, bf16 input (h1).
// ---------------------------------------------------------------------------
__global__ __launch_bounds__(256) void dense_fused_b(
    const unsigned short* __restrict__ hsrc, // N x 128 bf16
    const unsigned short* __restrict__ Wc,   // 256 x 128 bf16
    const float* __restrict__ W_a,
    unsigned short* __restrict__ z,
    unsigned short* __restrict__ zi,
    float* __restrict__ s_src0, float* __restrict__ s_src1,
    float* __restrict__ s_dst0, float* __restrict__ s_dst1)
{
    __shared__ unsigned short Ht[64 * LSTR];

    const int nodebase = blockIdx.x * 64;
    const int t = threadIdx.x;

    {
        int r = t >> 2, c0 = (t & 3) * 32;
        int node = nodebase + r;
        unsigned short* dst = Ht + r * LSTR + c0;
        if (node < N_NODES) {
            const unsigned short* src = hsrc + (size_t)node * DIM + c0;
#pragma unroll
            for (int i = 0; i < 4; i++)
                *(uint4*)(dst + i * 8) = *(const uint4*)(src + i * 8);
        } else {
            uint4 zr4 = make_uint4(0, 0, 0, 0);
#pragma unroll
            for (int i = 0; i < 4; i++) *(uint4*)(dst + i * 8) = zr4;
        }
    }
    __syncthreads();

    const int wave = t >> 6;
    const int lane = t & 63;
    const int n16 = lane & 15;
    const int quad = lane >> 4;
    const int node = nodebase + wave * 16 + n16;

    bf16x8 hfrag[4];
    const unsigned short* hrow = Ht + (wave * 16 + n16) * LSTR + quad * 8;
#pragma unroll
    for (int ks = 0; ks < 4; ks++)
        hfrag[ks] = *(const bf16x8*)(hrow + ks * 32);

#pragma unroll
    for (int cb = 0; cb < 4; cb++) {
        f32x4 acc[4];
#pragma unroll
        for (int ct = 0; ct < 4; ct++) {
            const unsigned short* wrow =
                Wc + (size_t)(cb * 64 + ct * 16 + n16) * DIM + quad * 8;
            f32x4 a = {0.f, 0.f, 0.f, 0.f};
#pragma unroll
            for (int ks = 0; ks < 4; ks++)
                a = __builtin_amdgcn_mfma_f32_16x16x32_bf16(
                        *(const bf16x8*)(wrow + ks * 32), hfrag[ks], a, 0, 0, 0);
            acc[ct] = a;
        }

        if (node < N_NODES) {
            unsigned short* zout = (cb < 2 ? z : zi);
            unsigned short* orow = zout + (size_t)node * DIM + (cb & 1) * 64 + quad * 4;
#pragma unroll
            for (int ct = 0; ct < 4; ct++) {
                uint2 pk;
                pk.x = (unsigned int)f2bf(acc[ct][0]) | ((unsigned int)f2bf(acc[ct][1]) << 16);
                pk.y = (unsigned int)f2bf(acc[ct][2]) | ((unsigned int)f2bf(acc[ct][3]) << 16);
                *(uint2*)(orow + ct * 16) = pk;
            }
        }

        if (cb < 2) {
            float ps = 0.f, pd = 0.f;
#pragma unroll
            for (int ct = 0; ct < 4; ct++) {
                float4 as = *(const float4*)(W_a + cb * 64 + ct * 16 + quad * 4);
                float4 ad = *(const float4*)(W_a + DIM + cb * 64 + ct * 16 + quad * 4);
                ps += acc[ct][0] * as.x + acc[ct][1] * as.y
                    + acc[ct][2] * as.z + acc[ct][3] * as.w;
                pd += acc[ct][0] * ad.x + acc[ct][1] * ad.y
                    + acc[ct][2] * ad.z + acc[ct][3] * ad.w;
            }
            ps += __shfl_xor(ps, 16); ps += __shfl_xor(ps, 32);
            pd += __shfl_xor(pd, 16); pd += __shfl_xor(pd, 32);
            if (lane < 16 && node < N_NODES) {
                (cb == 0 ? s_src0 : s_src1)[node] = ps;
                (cb == 0 ? s_dst0 : s_dst1)[node] = pd;
            }
        }
    }
}

// ---------------------------------------------------------------------------
// alpha_k: per-edge softmax coefficients -> alpha[E] f32.
// ---------------------------------------------------------------------------
__global__ __launch_bounds__(256) void alpha_k(
    const float* __restrict__ s_src0, const float* __restrict__ s_src1,
    const float* __restrict__ s_dst0, const float* __restrict__ s_dst1,
    const float* __restrict__ edge_d,
    const int* __restrict__ edge_src,
    const float* __restrict__ W_V,
    const float* __restrict__ W_a,
    float* __restrict__ alpha)
{
    const int e = blockIdx.x * 256 + threadIdx.x;   // 0..E-1
    const int node = e >> 4;                         // edge_dst
    int   s  = edge_src[e];
    float ed = edge_d[e];
    float coef = W_V[0] * W_a[2 * DIM];
    float x = (s_src0[s] + s_src1[s]) + (s_dst0[node] + s_dst1[node]) + ed * coef;
    x = x > 0.f ? x : 0.01f * x;
    float m = x;
    m = fmaxf(m, __shfl_xor(m, 1));
    m = fmaxf(m, __shfl_xor(m, 2));
    m = fmaxf(m, __shfl_xor(m, 4));
    m = fmaxf(m, __shfl_xor(m, 8));
    float ex = __expf(x - m);
    float d = ex;
    d += __shfl_xor(d, 1); d += __shfl_xor(d, 2);
    d += __shfl_xor(d, 4); d += __shfl_xor(d, 8);
    alpha[e] = ex / d;
}

// ---------------------------------------------------------------------------
// aggr_row: full-row softmax-aggregate (validated round 5: 73% occ, fetch
// floor, 3.7 TB/s). Writes h1 (bf16).
// ---------------------------------------------------------------------------
__global__ __launch_bounds__(256) void aggr_row(
    const unsigned short* __restrict__ z,    // N x 128 bf16
    const unsigned short* __restrict__ zi,   // N x 128 bf16
    const float* __restrict__ alpha,         // E f32
    const int* __restrict__ edge_src,
    unsigned short* __restrict__ hout)       // N x 128 bf16
{
    __shared__ float alpha_s[256];
    __shared__ int   src_s[256];

    const int t = threadIdx.x;
    const int base = blockIdx.x * 16;        // 16 nodes/block

    {
        int e0 = base * DEG + t;             // 256 consecutive edges
        alpha_s[t] = alpha[e0];
        src_s[t]   = edge_src[e0];
    }
    __syncthreads();

    const int nl = t >> 4;                   // node in block
    const int j  = t & 15;                   // col-group
    const int node = base + nl;
    const int c8 = j * 8;
    const unsigned short* zc = z + c8;

    float acc[8] = {};
#pragma unroll
    for (int e = 0; e < DEG; e++) {
        int   sj = src_s[nl * 16 + e];
        float a  = alpha_s[nl * 16 + e];
        uint4 r = *(const uint4*)(zc + (size_t)sj * DIM);
        acc[0] += a * bf2f((unsigned short)(r.x & 0xffff));
        acc[1] += a * bf2f((unsigned short)(r.x >> 16));
        acc[2] += a * bf2f((unsigned short)(r.y & 0xffff));
        acc[3] += a * bf2f((unsigned short)(r.y >> 16));
        acc[4] += a * bf2f((unsigned short)(r.z & 0xffff));
        acc[5] += a * bf2f((unsigned short)(r.z >> 16));
        acc[6] += a * bf2f((unsigned short)(r.w & 0xffff));
        acc[7] += a * bf2f((unsigned short)(r.w >> 16));
    }

    uint4 zr = *(const uint4*)(zi + (size_t)node * DIM + c8);
    float v[8];
    v[0] = fmaxf(bf2f((unsigned short)(zr.x & 0xffff)) + acc[0], 0.f);
    v[1] = fmaxf(bf2f((unsigned short)(zr.x >> 16)) + acc[1], 0.f);
    v[2] = fmaxf(bf2f((unsigned short)(zr.y & 0xffff)) + acc[2], 0.f);
    v[3] = fmaxf(bf2f((unsigned short)(zr.y >> 16)) + acc[3], 0.f);
    v[4] = fmaxf(bf2f((unsigned short)(zr.z & 0xffff)) + acc[4], 0.f);
    v[5] = fmaxf(bf2f((unsigned short)(zr.z >> 16)) + acc[5], 0.f);
    v[6] = fmaxf(bf2f((unsigned short)(zr.w & 0xffff)) + acc[6], 0.f);
    v[7] = fmaxf(bf2f((unsigned short)(zr.w >> 16)) + acc[7], 0.f);

    uint4 pk;
    pk.x = (unsigned int)f2bf(v[0]) | ((unsigned int)f2bf(v[1]) << 16);
    pk.y = (unsigned int)f2bf(v[2]) | ((unsigned int)f2bf(v[3]) << 16);
    pk.z = (unsigned int)f2bf(v[4]) | ((unsigned int)f2bf(v[5]) << 16);
    pk.w = (unsigned int)f2bf(v[6]) | ((unsigned int)f2bf(v[7]) << 16);
    *(uint4*)(hout + (size_t)node * DIM + c8) = pk;
}

// ---------------------------------------------------------------------------
// aggr_row_final: same structure, f32 output.
// ---------------------------------------------------------------------------
__global__ __launch_bounds__(256) void aggr_row_final(
    const unsigned short* __restrict__ z,    // z2
    const unsigned short* __restrict__ zi,   // zi2
    const float* __restrict__ alpha,
    const int* __restrict__ edge_src,
    float* __restrict__ out_f32)
{
    __shared__ float alpha_s[256];
    __shared__ int   src_s[256];

    const int t = threadIdx.x;
    const int base = blockIdx.x * 16;

    {
        int e0 = base * DEG + t;
        alpha_s[t] = alpha[e0];
        src_s[t]   = edge_src[e0];
    }
    __syncthreads();

    const int nl = t >> 4;
    const int j  = t & 15;
    const int node = base + nl;
    const int c8 = j * 8;
    const unsigned short* zc = z + c8;

    float acc[8] = {};
#pragma unroll
    for (int e = 0; e < DEG; e++) {
        int   sj = src_s[nl * 16 + e];
        float a  = alpha_s[nl * 16 + e];
        uint4 r = *(const uint4*)(zc + (size_t)sj * DIM);
        acc[0] += a * bf2f((unsigned short)(r.x & 0xffff));
        acc[1] += a * bf2f((unsigned short)(r.x >> 16));
        acc[2] += a * bf2f((unsigned short)(r.y & 0xffff));
        acc[3] += a * bf2f((unsigned short)(r.y >> 16));
        acc[4] += a * bf2f((unsigned short)(r.z & 0xffff));
        acc[5] += a * bf2f((unsigned short)(r.z >> 16));
        acc[6] += a * bf2f((unsigned short)(r.w & 0xffff));
        acc[7] += a * bf2f((unsigned short)(r.w >> 16));
    }

    uint4 zr = *(const uint4*)(zi + (size_t)node * DIM + c8);
    float* op = out_f32 + (size_t)node * DIM + c8;
    f32x4 o0, o1;
    o0[0] = fmaxf(bf2f((unsigned short)(zr.x & 0xffff)) + acc[0], 0.f);
    o0[1] = fmaxf(bf2f((unsigned short)(zr.x >> 16)) + acc[1], 0.f);
    o0[2] = fmaxf(bf2f((unsigned short)(zr.y & 0xffff)) + acc[2], 0.f);
    o0[3] = fmaxf(bf2f((unsigned short)(zr.y >> 16)) + acc[3], 0.f);
    o1[0] = fmaxf(bf2f((unsigned short)(zr.z & 0xffff)) + acc[4], 0.f);
    o1[1] = fmaxf(bf2f((unsigned short)(zr.z >> 16)) + acc[5], 0.f);
    o1[2] = fmaxf(bf2f((unsigned short)(zr.w & 0xffff)) + acc[6], 0.f);
    o1[3] = fmaxf(bf2f((unsigned short)(zr.w >> 16)) + acc[7], 0.f);
    __builtin_nontemporal_store(o0, (f32x4*)op);
    __builtin_nontemporal_store(o1, (f32x4*)(op + 4));
}

// ---------------------------------------------------------------------------
extern "C" void kernel_launch(void* const* d_in, const int* in_sizes, int n_in,
                              void* d_out, int out_size, void* d_ws, size_t ws_size,
                              hipStream_t stream) {
    const float* attr     = (const float*)d_in[0];
    const float* edge_d   = (const float*)d_in[1];
    const float* W_V1     = (const float*)d_in[2];
    const float* W_W1     = (const float*)d_in[3];
    const float* W_U1     = (const float*)d_in[4];
    const float* W_a1     = (const float*)d_in[5];
    const float* W_V2     = (const float*)d_in[6];
    const float* W_W2     = (const float*)d_in[7];
    const float* W_U2     = (const float*)d_in[8];
    const float* W_a2     = (const float*)d_in[9];
    const int*   edge_src = (const int*)d_in[10];

    float* out = (float*)d_out;

    char* ws = (char*)d_ws;
    unsigned short* z1    = (unsigned short*)ws;                       // 25.6 MB
    unsigned short* zi1   = (unsigned short*)(ws + 26u * 1024 * 1024); // 25.6 MB
    unsigned short* h1    = (unsigned short*)(ws + 52u * 1024 * 1024); // 25.6 MB
    unsigned short* Wc1   = (unsigned short*)(ws + 78u * 1024 * 1024);
    unsigned short* Wc2   = (unsigned short*)(ws + 79u * 1024 * 1024);
    float* s_src0         = (float*)(ws + 80u * 1024 * 1024);
    float* s_src1         = (float*)(ws + 81u * 1024 * 1024);
    float* s_dst0         = (float*)(ws + 82u * 1024 * 1024);
    float* s_dst1         = (float*)(ws + 83u * 1024 * 1024);
    float* alphaA         = (float*)(ws + 84u * 1024 * 1024);          // 6.4 MB
    // z2/zi2 overlay z1/zi1 (strictly sequential dependencies)
    unsigned short* z2  = z1;
    unsigned short* zi2 = zi1;

    prep_w<<<256, 256, 0, stream>>>(W_W1, W_U1, W_W2, W_U2, Wc1, Wc2);

    // ---- layer 1 ----
    dense_fused<<<NTILES, 256, 0, stream>>>(attr, Wc1, W_a1, z1, zi1,
                                            s_src0, s_src1, s_dst0, s_dst1);

    alpha_k<<<6250, 256, 0, stream>>>(s_src0, s_src1, s_dst0, s_dst1,
                                      edge_d, edge_src, W_V1, W_a1, alphaA);

    aggr_row<<<6250, 256, 0, stream>>>(z1, zi1, alphaA, edge_src, h1);

    // ---- layer 2 ----
    dense_fused_b<<<NTILES, 256, 0, stream>>>(h1, Wc2, W_a2, z2, zi2,
                                              s_src0, s_src1, s_dst0, s_dst1);

    alpha_k<<<6250, 256, 0, stream>>>(s_src0, s_src1, s_dst0, s_dst1,
                                      edge_d, edge_src, W_V2, W_a2, alphaA);

    aggr_row_final<<<6250, 256, 0, stream>>>(z2, zi2, alphaA, edge_src, out);
}

// Round 7
// 357.628 us; speedup vs baseline: 1.1455x; 1.1455x over previous
//
#include <hip/hip_runtime.h>

#define N_NODES 100000
#define NPAD 100032
#define DEG 16
#define DIM 128
#define E_EDGES 1600000
#define NTILES 1563          // ceil(100000/64)
#define DGRID (196 * 4 * 8)  // 6272 XCD-swizzled (tile, col-block) blocks
#define LSTR 136             // LDS row stride in shorts (16B-aligned, conflict-light)

typedef short bf16x8 __attribute__((ext_vector_type(8)));
typedef float f32x4 __attribute__((ext_vector_type(4)));

__device__ __forceinline__ unsigned short f2bf(float f) {
    unsigned int u = __builtin_bit_cast(unsigned int, f);
    u = (u + 0x7fffu + ((u >> 16) & 1u)) >> 16;
    return (unsigned short)u;
}
__device__ __forceinline__ float bf2f(unsigned short h) {
    unsigned int u = ((unsigned int)h) << 16;
    return __builtin_bit_cast(float, u);
}
__device__ __forceinline__ bf16x8 pack_bf16x8(float4 lo, float4 hi) {
    bf16x8 f;
    f[0] = (short)f2bf(lo.x); f[1] = (short)f2bf(lo.y);
    f[2] = (short)f2bf(lo.z); f[3] = (short)f2bf(lo.w);
    f[4] = (short)f2bf(hi.x); f[5] = (short)f2bf(hi.y);
    f[6] = (short)f2bf(hi.z); f[7] = (short)f2bf(hi.w);
    return f;
}

// ---------------------------------------------------------------------------
// prep_all: attr f32 -> attrb bf16 (padded rows zeroed), W casts, h1 pad zero.
// One dispatch replaces prep_w + a separate cast kernel.
//   blocks [0, 6252)   : attr cast, 2048 elems/block (6252*2048 = 100032*128)
//   blocks [6252, 6284): W_W1|W_U1 -> Wc1, W_W2|W_U2 -> Wc2 (65536 elems)
//   block  6284        : zero h1 pad rows 100000..100031
// ---------------------------------------------------------------------------
__global__ __launch_bounds__(256) void prep_all(
    const float* __restrict__ attr,
    const float* __restrict__ W_W1, const float* __restrict__ W_U1,
    const float* __restrict__ W_W2, const float* __restrict__ W_U2,
    unsigned short* __restrict__ attrb,
    unsigned short* __restrict__ Wc1, unsigned short* __restrict__ Wc2,
    unsigned short* __restrict__ h1)
{
    const int b = blockIdx.x;
    const int t = threadIdx.x;
    if (b < 6252) {
        size_t g = (size_t)b * 2048 + (size_t)t * 8;     // 8 elems/thread
        float4 v0 = make_float4(0.f, 0.f, 0.f, 0.f);
        float4 v1 = v0;
        if (g < (size_t)N_NODES * DIM) {                 // 12.8M % 8 == 0: all-or-none
            v0 = *(const float4*)(attr + g);
            v1 = *(const float4*)(attr + g + 4);
        }
        *(bf16x8*)(attrb + g) = pack_bf16x8(v0, v1);
    } else if (b < 6284) {
        int g = (b - 6252) * 2048 + t * 8;               // 0..65535, runs never straddle
        int half = g & 32767;
        const float* src = (g < 32768)
            ? (half < 16384 ? W_W1 + half : W_U1 + (half - 16384))
            : (half < 16384 ? W_W2 + half : W_U2 + (half - 16384));
        unsigned short* dst = (g < 32768) ? Wc1 + half : Wc2 + half;
        float4 v0 = *(const float4*)(src);
        float4 v1 = *(const float4*)(src + 4);
        *(bf16x8*)(dst) = pack_bf16x8(v0, v1);
    } else {
        unsigned short* p = h1 + (size_t)N_NODES * DIM;  // 32 rows * 128 = 4096 shorts
        *(uint4*)(p + t * 16) = make_uint4(0, 0, 0, 0);
        *(uint4*)(p + t * 16 + 8) = make_uint4(0, 0, 0, 0);
    }
}

// ---------------------------------------------------------------------------
// dense_g: z = h @ W_W^T, zi = h @ W_U^T (bf16 in/out) + score partials.
// Block = 64 nodes x 64 output cols, XCD-swizzled (4 cb-blocks of a tile on
// one XCD -> H rows L2-reused). W slice staged in LDS (17.4 KB, the ONLY
// LDS use -> 8 blocks/CU). H fragments loaded per-lane straight from global
// (16B/lane at 256B node stride = the proven 3.7 TB/s aggr pattern, 100%
// line utilization), issued BEFORE the W stage so their latency hides under
// staging + barrier. Round-6 lesson: W stays in LDS (per-MFMA global W reads
// were the latency chain); H needs no LDS (read once, lane-private).
// ---------------------------------------------------------------------------
__global__ __launch_bounds__(256) void dense_g(
    const unsigned short* __restrict__ hsrc, // NPAD x 128 bf16 (pad rows zero)
    const unsigned short* __restrict__ Wc,   // 256 x 128 bf16 (W_W|W_U)
    const float* __restrict__ W_a,           // 257 f32
    unsigned short* __restrict__ z,
    unsigned short* __restrict__ zi,
    float* __restrict__ s_src0, float* __restrict__ s_src1,
    float* __restrict__ s_dst0, float* __restrict__ s_dst1)
{
    __shared__ unsigned short Wt[64 * LSTR];

    const int bid = blockIdx.x;
    const int xcd = bid & 7;
    const int q = bid >> 3;
    const int cb = q & 3;                    // col-block 0..3
    const int tile = (q >> 2) * 8 + xcd;
    if (tile >= NTILES) return;
    const int nodebase = tile * 64;
    const int t = threadIdx.x;
    const int wave = t >> 6;
    const int lane = t & 63;
    const int n16 = lane & 15;
    const int quad = lane >> 4;
    const int node = nodebase + wave * 16 + n16;

    // ---- issue H fragment loads first (global, latency hides under stage) ----
    bf16x8 hfrag[4];
    const unsigned short* hrow = hsrc + (size_t)node * DIM + quad * 8;
#pragma unroll
    for (int ks = 0; ks < 4; ks++)
        hfrag[ks] = *(const bf16x8*)(hrow + ks * 32);

    // ---- stage W slice into LDS ----
    {
        int r = t >> 2, c0 = (t & 3) * 32;
        const unsigned short* src = Wc + (size_t)(cb * 64 + r) * DIM + c0;
        unsigned short* dst = Wt + r * LSTR + c0;
#pragma unroll
        for (int i = 0; i < 4; i++)
            *(uint4*)(dst + i * 8) = *(const uint4*)(src + i * 8);
    }
    __syncthreads();

    f32x4 acc[4];
#pragma unroll
    for (int ct = 0; ct < 4; ct++) {
        const unsigned short* wrow = Wt + (ct * 16 + n16) * LSTR + quad * 8;
        f32x4 a = {0.f, 0.f, 0.f, 0.f};
#pragma unroll
        for (int ks = 0; ks < 4; ks++)
            a = __builtin_amdgcn_mfma_f32_16x16x32_bf16(
                    *(const bf16x8*)(wrow + ks * 32), hfrag[ks], a, 0, 0, 0);
        acc[ct] = a;
    }

    if (node < N_NODES) {
        unsigned short* zout = (cb < 2 ? z : zi);
        unsigned short* orow = zout + (size_t)node * DIM + (cb & 1) * 64 + quad * 4;
#pragma unroll
        for (int ct = 0; ct < 4; ct++) {
            uint2 pk;
            pk.x = (unsigned int)f2bf(acc[ct][0]) | ((unsigned int)f2bf(acc[ct][1]) << 16);
            pk.y = (unsigned int)f2bf(acc[ct][2]) | ((unsigned int)f2bf(acc[ct][3]) << 16);
            *(uint2*)(orow + ct * 16) = pk;
        }
    }

    if (cb < 2) {
        float ps = 0.f, pd = 0.f;
#pragma unroll
        for (int ct = 0; ct < 4; ct++) {
            float4 as = *(const float4*)(W_a + cb * 64 + ct * 16 + quad * 4);
            float4 ad = *(const float4*)(W_a + DIM + cb * 64 + ct * 16 + quad * 4);
            ps += acc[ct][0] * as.x + acc[ct][1] * as.y
                + acc[ct][2] * as.z + acc[ct][3] * as.w;
            pd += acc[ct][0] * ad.x + acc[ct][1] * ad.y
                + acc[ct][2] * ad.z + acc[ct][3] * ad.w;
        }
        ps += __shfl_xor(ps, 16); ps += __shfl_xor(ps, 32);
        pd += __shfl_xor(pd, 16); pd += __shfl_xor(pd, 32);
        if (lane < 16 && node < N_NODES) {
            (cb == 0 ? s_src0 : s_src1)[node] = ps;
            (cb == 0 ? s_dst0 : s_dst1)[node] = pd;
        }
    }
}

// ---------------------------------------------------------------------------
// alpha_k: per-edge softmax coefficients -> alpha[E] f32. (validated r5/r6)
// ---------------------------------------------------------------------------
__global__ __launch_bounds__(256) void alpha_k(
    const float* __restrict__ s_src0, const float* __restrict__ s_src1,
    const float* __restrict__ s_dst0, const float* __restrict__ s_dst1,
    const float* __restrict__ edge_d,
    const int* __restrict__ edge_src,
    const float* __restrict__ W_V,
    const float* __restrict__ W_a,
    float* __restrict__ alpha)
{
    const int e = blockIdx.x * 256 + threadIdx.x;   // 0..E-1
    const int node = e >> 4;                         // edge_dst
    int   s  = edge_src[e];
    float ed = edge_d[e];
    float coef = W_V[0] * W_a[2 * DIM];
    float x = (s_src0[s] + s_src1[s]) + (s_dst0[node] + s_dst1[node]) + ed * coef;
    x = x > 0.f ? x : 0.01f * x;
    float m = x;
    m = fmaxf(m, __shfl_xor(m, 1));
    m = fmaxf(m, __shfl_xor(m, 2));
    m = fmaxf(m, __shfl_xor(m, 4));
    m = fmaxf(m, __shfl_xor(m, 8));
    float ex = __expf(x - m);
    float d = ex;
    d += __shfl_xor(d, 1); d += __shfl_xor(d, 2);
    d += __shfl_xor(d, 4); d += __shfl_xor(d, 8);
    alpha[e] = ex / d;
}

// ---------------------------------------------------------------------------
// aggr_row: full-row softmax-aggregate (validated round 5: 73% occ, fetch
// floor, 3.7 TB/s). Writes h1 (bf16).
// ---------------------------------------------------------------------------
__global__ __launch_bounds__(256) void aggr_row(
    const unsigned short* __restrict__ z,    // N x 128 bf16
    const unsigned short* __restrict__ zi,   // N x 128 bf16
    const float* __restrict__ alpha,         // E f32
    const int* __restrict__ edge_src,
    unsigned short* __restrict__ hout)       // NPAD x 128 bf16
{
    __shared__ float alpha_s[256];
    __shared__ int   src_s[256];

    const int t = threadIdx.x;
    const int base = blockIdx.x * 16;        // 16 nodes/block

    {
        int e0 = base * DEG + t;             // 256 consecutive edges
        alpha_s[t] = alpha[e0];
        src_s[t]   = edge_src[e0];
    }
    __syncthreads();

    const int nl = t >> 4;                   // node in block
    const int j  = t & 15;                   // col-group
    const int node = base + nl;
    const int c8 = j * 8;
    const unsigned short* zc = z + c8;

    float acc[8] = {};
#pragma unroll
    for (int e = 0; e < DEG; e++) {
        int   sj = src_s[nl * 16 + e];
        float a  = alpha_s[nl * 16 + e];
        uint4 r = *(const uint4*)(zc + (size_t)sj * DIM);
        acc[0] += a * bf2f((unsigned short)(r.x & 0xffff));
        acc[1] += a * bf2f((unsigned short)(r.x >> 16));
        acc[2] += a * bf2f((unsigned short)(r.y & 0xffff));
        acc[3] += a * bf2f((unsigned short)(r.y >> 16));
        acc[4] += a * bf2f((unsigned short)(r.z & 0xffff));
        acc[5] += a * bf2f((unsigned short)(r.z >> 16));
        acc[6] += a * bf2f((unsigned short)(r.w & 0xffff));
        acc[7] += a * bf2f((unsigned short)(r.w >> 16));
    }

    uint4 zr = *(const uint4*)(zi + (size_t)node * DIM + c8);
    float v[8];
    v[0] = fmaxf(bf2f((unsigned short)(zr.x & 0xffff)) + acc[0], 0.f);
    v[1] = fmaxf(bf2f((unsigned short)(zr.x >> 16)) + acc[1], 0.f);
    v[2] = fmaxf(bf2f((unsigned short)(zr.y & 0xffff)) + acc[2], 0.f);
    v[3] = fmaxf(bf2f((unsigned short)(zr.y >> 16)) + acc[3], 0.f);
    v[4] = fmaxf(bf2f((unsigned short)(zr.z & 0xffff)) + acc[4], 0.f);
    v[5] = fmaxf(bf2f((unsigned short)(zr.z >> 16)) + acc[5], 0.f);
    v[6] = fmaxf(bf2f((unsigned short)(zr.w & 0xffff)) + acc[6], 0.f);
    v[7] = fmaxf(bf2f((unsigned short)(zr.w >> 16)) + acc[7], 0.f);

    uint4 pk;
    pk.x = (unsigned int)f2bf(v[0]) | ((unsigned int)f2bf(v[1]) << 16);
    pk.y = (unsigned int)f2bf(v[2]) | ((unsigned int)f2bf(v[3]) << 16);
    pk.z = (unsigned int)f2bf(v[4]) | ((unsigned int)f2bf(v[5]) << 16);
    pk.w = (unsigned int)f2bf(v[6]) | ((unsigned int)f2bf(v[7]) << 16);
    *(uint4*)(hout + (size_t)node * DIM + c8) = pk;
}

// ---------------------------------------------------------------------------
// aggr_row_final: same structure, f32 output.
// ---------------------------------------------------------------------------
__global__ __launch_bounds__(256) void aggr_row_final(
    const unsigned short* __restrict__ z,    // z2
    const unsigned short* __restrict__ zi,   // zi2
    const float* __restrict__ alpha,
    const int* __restrict__ edge_src,
    float* __restrict__ out_f32)
{
    __shared__ float alpha_s[256];
    __shared__ int   src_s[256];

    const int t = threadIdx.x;
    const int base = blockIdx.x * 16;

    {
        int e0 = base * DEG + t;
        alpha_s[t] = alpha[e0];
        src_s[t]   = edge_src[e0];
    }
    __syncthreads();

    const int nl = t >> 4;
    const int j  = t & 15;
    const int node = base + nl;
    const int c8 = j * 8;
    const unsigned short* zc = z + c8;

    float acc[8] = {};
#pragma unroll
    for (int e = 0; e < DEG; e++) {
        int   sj = src_s[nl * 16 + e];
        float a  = alpha_s[nl * 16 + e];
        uint4 r = *(const uint4*)(zc + (size_t)sj * DIM);
        acc[0] += a * bf2f((unsigned short)(r.x & 0xffff));
        acc[1] += a * bf2f((unsigned short)(r.x >> 16));
        acc[2] += a * bf2f((unsigned short)(r.y & 0xffff));
        acc[3] += a * bf2f((unsigned short)(r.y >> 16));
        acc[4] += a * bf2f((unsigned short)(r.z & 0xffff));
        acc[5] += a * bf2f((unsigned short)(r.z >> 16));
        acc[6] += a * bf2f((unsigned short)(r.w & 0xffff));
        acc[7] += a * bf2f((unsigned short)(r.w >> 16));
    }

    uint4 zr = *(const uint4*)(zi + (size_t)node * DIM + c8);
    float* op = out_f32 + (size_t)node * DIM + c8;
    f32x4 o0, o1;
    o0[0] = fmaxf(bf2f((unsigned short)(zr.x & 0xffff)) + acc[0], 0.f);
    o0[1] = fmaxf(bf2f((unsigned short)(zr.x >> 16)) + acc[1], 0.f);
    o0[2] = fmaxf(bf2f((unsigned short)(zr.y & 0xffff)) + acc[2], 0.f);
    o0[3] = fmaxf(bf2f((unsigned short)(zr.y >> 16)) + acc[3], 0.f);
    o1[0] = fmaxf(bf2f((unsigned short)(zr.z & 0xffff)) + acc[4], 0.f);
    o1[1] = fmaxf(bf2f((unsigned short)(zr.z >> 16)) + acc[5], 0.f);
    o1[2] = fmaxf(bf2f((unsigned short)(zr.w & 0xffff)) + acc[6], 0.f);
    o1[3] = fmaxf(bf2f((unsigned short)(zr.w >> 16)) + acc[7], 0.f);
    __builtin_nontemporal_store(o0, (f32x4*)op);
    __builtin_nontemporal_store(o1, (f32x4*)(op + 4));
}

// ---------------------------------------------------------------------------
extern "C" void kernel_launch(void* const* d_in, const int* in_sizes, int n_in,
                              void* d_out, int out_size, void* d_ws, size_t ws_size,
                              hipStream_t stream) {
    const float* attr     = (const float*)d_in[0];
    const float* edge_d   = (const float*)d_in[1];
    const float* W_V1     = (const float*)d_in[2];
    const float* W_W1     = (const float*)d_in[3];
    const float* W_U1     = (const float*)d_in[4];
    const float* W_a1     = (const float*)d_in[5];
    const float* W_V2     = (const float*)d_in[6];
    const float* W_W2     = (const float*)d_in[7];
    const float* W_U2     = (const float*)d_in[8];
    const float* W_a2     = (const float*)d_in[9];
    const int*   edge_src = (const int*)d_in[10];

    float* out = (float*)d_out;

    char* ws = (char*)d_ws;
    unsigned short* z1    = (unsigned short*)ws;                       // 26 MB
    unsigned short* zi1   = (unsigned short*)(ws + 26u * 1024 * 1024); // 26 MB
    unsigned short* h1    = (unsigned short*)(ws + 52u * 1024 * 1024); // 26 MB (NPAD rows)
    unsigned short* attrb = (unsigned short*)(ws + 78u * 1024 * 1024); // 26 MB (NPAD rows)
    unsigned short* Wc1   = (unsigned short*)(ws + 104u * 1024 * 1024);
    unsigned short* Wc2   = (unsigned short*)(ws + 105u * 1024 * 1024);
    float* s_src0         = (float*)(ws + 106u * 1024 * 1024);
    float* s_src1         = (float*)(ws + 107u * 1024 * 1024);
    float* s_dst0         = (float*)(ws + 108u * 1024 * 1024);
    float* s_dst1         = (float*)(ws + 109u * 1024 * 1024);
    // alphaA overlays attrb (attrb dead after dense_g layer 1; alpha written after)
    float* alphaA         = (float*)(ws + 78u * 1024 * 1024);          // 6.4 MB
    // z2/zi2 overlay z1/zi1 (strictly sequential dependencies)
    unsigned short* z2  = z1;
    unsigned short* zi2 = zi1;

    prep_all<<<6285, 256, 0, stream>>>(attr, W_W1, W_U1, W_W2, W_U2,
                                       attrb, Wc1, Wc2, h1);

    // ---- layer 1 ----
    dense_g<<<DGRID, 256, 0, stream>>>(attrb, Wc1, W_a1, z1, zi1,
                                       s_src0, s_src1, s_dst0, s_dst1);

    alpha_k<<<6250, 256, 0, stream>>>(s_src0, s_src1, s_dst0, s_dst1,
                                      edge_d, edge_src, W_V1, W_a1, alphaA);

    aggr_row<<<6250, 256, 0, stream>>>(z1, zi1, alphaA, edge_src, h1);

    // ---- layer 2 ----
    dense_g<<<DGRID, 256, 0, stream>>>(h1, Wc2, W_a2, z2, zi2,
                                       s_src0, s_src1, s_dst0, s_dst1);

    alpha_k<<<6250, 256, 0, stream>>>(s_src0, s_src1, s_dst0, s_dst1,
                                      edge_d, edge_src, W_V2, W_a2, alphaA);

    aggr_row_final<<<6250, 256, 0, stream>>>(z2, zi2, alphaA, edge_src, out);
}

// Round 8
// 321.904 us; speedup vs baseline: 1.2726x; 1.1110x over previous
//
#include <hip/hip_runtime.h>

#define N_NODES 100000
#define NPAD 100032
#define DEG 16
#define DIM 128
#define E_EDGES 1600000
#define NTILES 1563          // ceil(100000/64)
#define DGRID (196 * 4 * 8)  // 6272 XCD-swizzled (tile, col-block) blocks
#define LSTR 136             // LDS row stride in shorts (16B-aligned, conflict-light)

typedef short bf16x8 __attribute__((ext_vector_type(8)));
typedef float f32x4 __attribute__((ext_vector_type(4)));

__device__ __forceinline__ unsigned short f2bf(float f) {
    unsigned int u = __builtin_bit_cast(unsigned int, f);
    u = (u + 0x7fffu + ((u >> 16) & 1u)) >> 16;
    return (unsigned short)u;
}
__device__ __forceinline__ float bf2f(unsigned short h) {
    unsigned int u = ((unsigned int)h) << 16;
    return __builtin_bit_cast(float, u);
}
__device__ __forceinline__ bf16x8 pack_bf16x8(float4 lo, float4 hi) {
    bf16x8 f;
    f[0] = (short)f2bf(lo.x); f[1] = (short)f2bf(lo.y);
    f[2] = (short)f2bf(lo.z); f[3] = (short)f2bf(lo.w);
    f[4] = (short)f2bf(hi.x); f[5] = (short)f2bf(hi.y);
    f[6] = (short)f2bf(hi.z); f[7] = (short)f2bf(hi.w);
    return f;
}

// ---------------------------------------------------------------------------
// prep_all: attr f32 -> attrb bf16 (pad rows zeroed), W casts.
//   blocks [0, 6252)   : attr cast (8 elems/thread)
//   blocks [6252, 6284): W_W1|W_U1 -> Wc1, W_W2|W_U2 -> Wc2
//   block  6284        : zero attrb pad rows 100000..100031
// ---------------------------------------------------------------------------
__global__ __launch_bounds__(256) void prep_all(
    const float* __restrict__ attr,
    const float* __restrict__ W_W1, const float* __restrict__ W_U1,
    const float* __restrict__ W_W2, const float* __restrict__ W_U2,
    unsigned short* __restrict__ attrb,
    unsigned short* __restrict__ Wc1, unsigned short* __restrict__ Wc2)
{
    const int b = blockIdx.x;
    const int t = threadIdx.x;
    if (b < 6252) {
        size_t g = (size_t)b * 2048 + (size_t)t * 8;
        float4 v0 = make_float4(0.f, 0.f, 0.f, 0.f);
        float4 v1 = v0;
        if (g < (size_t)N_NODES * DIM) {                 // 12.8M % 8 == 0: all-or-none
            v0 = *(const float4*)(attr + g);
            v1 = *(const float4*)(attr + g + 4);
        }
        *(bf16x8*)(attrb + g) = pack_bf16x8(v0, v1);
    } else if (b < 6284) {
        int g = (b - 6252) * 2048 + t * 8;               // 0..65535
        int half = g & 32767;
        const float* src = (g < 32768)
            ? (half < 16384 ? W_W1 + half : W_U1 + (half - 16384))
            : (half < 16384 ? W_W2 + half : W_U2 + (half - 16384));
        unsigned short* dst = (g < 32768) ? Wc1 + half : Wc2 + half;
        float4 v0 = *(const float4*)(src);
        float4 v1 = *(const float4*)(src + 4);
        *(bf16x8*)(dst) = pack_bf16x8(v0, v1);
    } else {
        unsigned short* p = attrb + (size_t)N_NODES * DIM; // 32 rows * 128 shorts
        *(uint4*)(p + t * 16) = make_uint4(0, 0, 0, 0);
        *(uint4*)(p + t * 16 + 8) = make_uint4(0, 0, 0, 0);
    }
}

// ---------------------------------------------------------------------------
// dense_g (r7, validated): z = h @ W_W^T, zi = h @ W_U^T + score partials.
// W slice in LDS (17.4 KB only -> 8 blocks/CU); H fragments straight from
// global (16B/lane, 256B stride), issued before the W stage. XCD-swizzled.
// ---------------------------------------------------------------------------
__global__ __launch_bounds__(256) void dense_g(
    const unsigned short* __restrict__ hsrc, // NPAD x 128 bf16 (pad rows zero)
    const unsigned short* __restrict__ Wc,   // 256 x 128 bf16 (W_W|W_U)
    const float* __restrict__ W_a,           // 257 f32
    unsigned short* __restrict__ z,
    unsigned short* __restrict__ zi,
    float* __restrict__ s_src0, float* __restrict__ s_src1,
    float* __restrict__ s_dst0, float* __restrict__ s_dst1)
{
    __shared__ unsigned short Wt[64 * LSTR];

    const int bid = blockIdx.x;
    const int xcd = bid & 7;
    const int q = bid >> 3;
    const int cb = q & 3;                    // col-block 0..3
    const int tile = (q >> 2) * 8 + xcd;
    if (tile >= NTILES) return;
    const int nodebase = tile * 64;
    const int t = threadIdx.x;
    const int wave = t >> 6;
    const int lane = t & 63;
    const int n16 = lane & 15;
    const int quad = lane >> 4;
    const int node = nodebase + wave * 16 + n16;

    // H fragment loads first (latency hides under W stage + barrier)
    bf16x8 hfrag[4];
    const unsigned short* hrow = hsrc + (size_t)node * DIM + quad * 8;
#pragma unroll
    for (int ks = 0; ks < 4; ks++)
        hfrag[ks] = *(const bf16x8*)(hrow + ks * 32);

    // stage W slice into LDS
    {
        int r = t >> 2, c0 = (t & 3) * 32;
        const unsigned short* src = Wc + (size_t)(cb * 64 + r) * DIM + c0;
        unsigned short* dst = Wt + r * LSTR + c0;
#pragma unroll
        for (int i = 0; i < 4; i++)
            *(uint4*)(dst + i * 8) = *(const uint4*)(src + i * 8);
    }
    __syncthreads();

    f32x4 acc[4];
#pragma unroll
    for (int ct = 0; ct < 4; ct++) {
        const unsigned short* wrow = Wt + (ct * 16 + n16) * LSTR + quad * 8;
        f32x4 a = {0.f, 0.f, 0.f, 0.f};
#pragma unroll
        for (int ks = 0; ks < 4; ks++)
            a = __builtin_amdgcn_mfma_f32_16x16x32_bf16(
                    *(const bf16x8*)(wrow + ks * 32), hfrag[ks], a, 0, 0, 0);
        acc[ct] = a;
    }

    if (node < N_NODES) {
        unsigned short* zout = (cb < 2 ? z : zi);
        unsigned short* orow = zout + (size_t)node * DIM + (cb & 1) * 64 + quad * 4;
#pragma unroll
        for (int ct = 0; ct < 4; ct++) {
            uint2 pk;
            pk.x = (unsigned int)f2bf(acc[ct][0]) | ((unsigned int)f2bf(acc[ct][1]) << 16);
            pk.y = (unsigned int)f2bf(acc[ct][2]) | ((unsigned int)f2bf(acc[ct][3]) << 16);
            *(uint2*)(orow + ct * 16) = pk;
        }
    }

    if (cb < 2) {
        float ps = 0.f, pd = 0.f;
#pragma unroll
        for (int ct = 0; ct < 4; ct++) {
            float4 as = *(const float4*)(W_a + cb * 64 + ct * 16 + quad * 4);
            float4 ad = *(const float4*)(W_a + DIM + cb * 64 + ct * 16 + quad * 4);
            ps += acc[ct][0] * as.x + acc[ct][1] * as.y
                + acc[ct][2] * as.z + acc[ct][3] * as.w;
            pd += acc[ct][0] * ad.x + acc[ct][1] * ad.y
                + acc[ct][2] * ad.z + acc[ct][3] * ad.w;
        }
        ps += __shfl_xor(ps, 16); ps += __shfl_xor(ps, 32);
        pd += __shfl_xor(pd, 16); pd += __shfl_xor(pd, 32);
        if (lane < 16 && node < N_NODES) {
            (cb == 0 ? s_src0 : s_src1)[node] = ps;
            (cb == 0 ? s_dst0 : s_dst1)[node] = pd;
        }
    }
}

// ---------------------------------------------------------------------------
// aggr_dense (r3, validated 101.5 us): 16 nodes/block. Fused shfl-softmax +
// gather-aggregate (h1 -> LDS only) + layer-2 dense + layer-2 score partials.
// Eliminates one alpha dispatch AND one dense dispatch.
// ---------------------------------------------------------------------------
__global__ __launch_bounds__(256) void aggr_dense(
    const unsigned short* __restrict__ z,    // z1
    const unsigned short* __restrict__ zi,   // zi1
    const float* __restrict__ s_src0, const float* __restrict__ s_src1,
    const float* __restrict__ s_dst0, const float* __restrict__ s_dst1,
    const float* __restrict__ edge_d,
    const int* __restrict__ edge_src,
    const float* __restrict__ W_V,           // W_V1 (1 float)
    const float* __restrict__ W_a,           // W_a1
    const unsigned short* __restrict__ Wc2,  // 256 x 128 bf16 (W_W2|W_U2)
    const float* __restrict__ W_a2,          // 257 f32 (layer-2 scores)
    unsigned short* __restrict__ z2,
    unsigned short* __restrict__ zi2,
    float* __restrict__ t_src0, float* __restrict__ t_src1,
    float* __restrict__ t_dst0, float* __restrict__ t_dst1)
{
    __shared__ unsigned short Hl[16 * LSTR];

    const int t = threadIdx.x;
    const int base = blockIdx.x * 16;
    const int nl = t >> 4;          // node within block 0..15
    const int j  = t & 15;          // edge index == col-slice index
    const int nodej = base + nl;
    const int lane = t & 63;
    const int gb = lane & 48;       // 16-lane group base within wave

    const int e = nodej * DEG + j;

    int   s  = __builtin_nontemporal_load(edge_src + e);
    float ed = __builtin_nontemporal_load(edge_d + e);

    float v_ss0 = s_src0[s];
    float v_ss1 = s_src1[s];
    float v_sd0 = s_dst0[nodej];
    float v_sd1 = s_dst1[nodej];

    const int c8 = j * 8;
    uint4 raw[DEG];
#pragma unroll
    for (int jj = 0; jj < DEG; jj++) {
        int sj = __shfl(s, gb | jj);
        raw[jj] = *(const uint4*)(z + (size_t)sj * DIM + c8);
    }
    uint4 zr = *(const uint4*)(zi + (size_t)nodej * DIM + c8);

    // ---- softmax (16-lane groups, all-shfl) ----
    float coef = W_V[0] * W_a[2 * DIM];
    float x = (v_ss0 + v_ss1) + (v_sd0 + v_sd1) + ed * coef;
    x = x > 0.f ? x : 0.01f * x;
    float m = x;
    m = fmaxf(m, __shfl_xor(m, 1));
    m = fmaxf(m, __shfl_xor(m, 2));
    m = fmaxf(m, __shfl_xor(m, 4));
    m = fmaxf(m, __shfl_xor(m, 8));
    float ex = __expf(x - m);
    float d = ex;
    d += __shfl_xor(d, 1); d += __shfl_xor(d, 2);
    d += __shfl_xor(d, 4); d += __shfl_xor(d, 8);
    float aj = ex / d;

    // ---- consume gathers ----
    float acc8[8] = {};
#pragma unroll
    for (int jj = 0; jj < DEG; jj++) {
        float a = __shfl(aj, gb | jj);
        acc8[0] += a * bf2f((unsigned short)raw[jj].x);
        acc8[1] += a * bf2f((unsigned short)(raw[jj].x >> 16));
        acc8[2] += a * bf2f((unsigned short)raw[jj].y);
        acc8[3] += a * bf2f((unsigned short)(raw[jj].y >> 16));
        acc8[4] += a * bf2f((unsigned short)raw[jj].z);
        acc8[5] += a * bf2f((unsigned short)(raw[jj].z >> 16));
        acc8[6] += a * bf2f((unsigned short)raw[jj].w);
        acc8[7] += a * bf2f((unsigned short)(raw[jj].w >> 16));
    }

    float v[8];
    v[0] = fmaxf(bf2f((unsigned short)zr.x) + acc8[0], 0.f);
    v[1] = fmaxf(bf2f((unsigned short)(zr.x >> 16)) + acc8[1], 0.f);
    v[2] = fmaxf(bf2f((unsigned short)zr.y) + acc8[2], 0.f);
    v[3] = fmaxf(bf2f((unsigned short)(zr.y >> 16)) + acc8[3], 0.f);
    v[4] = fmaxf(bf2f((unsigned short)zr.z) + acc8[4], 0.f);
    v[5] = fmaxf(bf2f((unsigned short)(zr.z >> 16)) + acc8[5], 0.f);
    v[6] = fmaxf(bf2f((unsigned short)zr.w) + acc8[6], 0.f);
    v[7] = fmaxf(bf2f((unsigned short)(zr.w >> 16)) + acc8[7], 0.f);

    {
        uint4 pk;
        pk.x = (unsigned int)f2bf(v[0]) | ((unsigned int)f2bf(v[1]) << 16);
        pk.y = (unsigned int)f2bf(v[2]) | ((unsigned int)f2bf(v[3]) << 16);
        pk.z = (unsigned int)f2bf(v[4]) | ((unsigned int)f2bf(v[5]) << 16);
        pk.w = (unsigned int)f2bf(v[6]) | ((unsigned int)f2bf(v[7]) << 16);
        *(uint4*)(Hl + nl * LSTR + c8) = pk;
    }
    __syncthreads();

    // ---- layer-2 dense for these 16 nodes ----
    const int wave = t >> 6;
    const int n16 = lane & 15;
    const int quad = lane >> 4;
    const int node = base + n16;

    bf16x8 hfrag[4];
    const unsigned short* hrow = Hl + n16 * LSTR + quad * 8;
#pragma unroll
    for (int ks = 0; ks < 4; ks++)
        hfrag[ks] = *(const bf16x8*)(hrow + ks * 32);

    f32x4 acc[4];
#pragma unroll
    for (int ct = 0; ct < 4; ct++) {
        const unsigned short* wrow = Wc2 + (size_t)(wave * 64 + ct * 16 + n16) * DIM + quad * 8;
        f32x4 a = {0.f, 0.f, 0.f, 0.f};
#pragma unroll
        for (int ks = 0; ks < 4; ks++)
            a = __builtin_amdgcn_mfma_f32_16x16x32_bf16(
                    *(const bf16x8*)(wrow + ks * 32), hfrag[ks], a, 0, 0, 0);
        acc[ct] = a;
    }

    {
        unsigned short* zout = (wave < 2 ? z2 : zi2);
        unsigned short* orow = zout + (size_t)node * DIM + (wave & 1) * 64 + quad * 4;
#pragma unroll
        for (int ct = 0; ct < 4; ct++) {
            uint2 pk;
            pk.x = (unsigned int)f2bf(acc[ct][0]) | ((unsigned int)f2bf(acc[ct][1]) << 16);
            pk.y = (unsigned int)f2bf(acc[ct][2]) | ((unsigned int)f2bf(acc[ct][3]) << 16);
            *(uint2*)(orow + ct * 16) = pk;
        }
    }

    if (wave < 2) {
        float ps = 0.f, pd = 0.f;
#pragma unroll
        for (int ct = 0; ct < 4; ct++) {
            float4 as = *(const float4*)(W_a2 + wave * 64 + ct * 16 + quad * 4);
            float4 ad = *(const float4*)(W_a2 + DIM + wave * 64 + ct * 16 + quad * 4);
            ps += acc[ct][0] * as.x + acc[ct][1] * as.y
                + acc[ct][2] * as.z + acc[ct][3] * as.w;
            pd += acc[ct][0] * ad.x + acc[ct][1] * ad.y
                + acc[ct][2] * ad.z + acc[ct][3] * ad.w;
        }
        ps += __shfl_xor(ps, 16); ps += __shfl_xor(ps, 32);
        pd += __shfl_xor(pd, 16); pd += __shfl_xor(pd, 32);
        if (lane < 16) {
            (wave == 0 ? t_src0 : t_src1)[node] = ps;
            (wave == 0 ? t_dst0 : t_dst1)[node] = pd;
        }
    }
}

// ---------------------------------------------------------------------------
// aggr_final (r3, validated): barrier-free, zero LDS, all-shfl softmax,
// f32 output (nt store, fully coalesced).
// ---------------------------------------------------------------------------
__global__ __launch_bounds__(256) void aggr_final(
    const unsigned short* __restrict__ z,    // z2
    const unsigned short* __restrict__ zi,   // zi2
    const float* __restrict__ s_src0, const float* __restrict__ s_src1,
    const float* __restrict__ s_dst0, const float* __restrict__ s_dst1,
    const float* __restrict__ edge_d,
    const int* __restrict__ edge_src,
    const float* __restrict__ W_V,           // W_V2
    const float* __restrict__ W_a,           // W_a2
    float* __restrict__ out_f32)
{
    const int t = threadIdx.x;
    const int base = blockIdx.x * 16;
    const int nl = t >> 4;
    const int j  = t & 15;
    const int node = base + nl;
    const int lane = t & 63;
    const int gb = lane & 48;

    const int e = node * DEG + j;

    int   s  = __builtin_nontemporal_load(edge_src + e);
    float ed = __builtin_nontemporal_load(edge_d + e);

    float v_ss0 = s_src0[s];
    float v_ss1 = s_src1[s];
    float v_sd0 = s_dst0[node];
    float v_sd1 = s_dst1[node];

    const int c8 = j * 8;
    uint4 raw[DEG];
#pragma unroll
    for (int jj = 0; jj < DEG; jj++) {
        int sj = __shfl(s, gb | jj);
        raw[jj] = *(const uint4*)(z + (size_t)sj * DIM + c8);
    }
    uint4 zr = *(const uint4*)(zi + (size_t)node * DIM + c8);

    float coef = W_V[0] * W_a[2 * DIM];
    float x = (v_ss0 + v_ss1) + (v_sd0 + v_sd1) + ed * coef;
    x = x > 0.f ? x : 0.01f * x;
    float m = x;
    m = fmaxf(m, __shfl_xor(m, 1));
    m = fmaxf(m, __shfl_xor(m, 2));
    m = fmaxf(m, __shfl_xor(m, 4));
    m = fmaxf(m, __shfl_xor(m, 8));
    float ex = __expf(x - m);
    float d = ex;
    d += __shfl_xor(d, 1); d += __shfl_xor(d, 2);
    d += __shfl_xor(d, 4); d += __shfl_xor(d, 8);
    float aj = ex / d;

    float acc[8] = {};
#pragma unroll
    for (int jj = 0; jj < DEG; jj++) {
        float a = __shfl(aj, gb | jj);
        acc[0] += a * bf2f((unsigned short)raw[jj].x);
        acc[1] += a * bf2f((unsigned short)(raw[jj].x >> 16));
        acc[2] += a * bf2f((unsigned short)raw[jj].y);
        acc[3] += a * bf2f((unsigned short)(raw[jj].y >> 16));
        acc[4] += a * bf2f((unsigned short)raw[jj].z);
        acc[5] += a * bf2f((unsigned short)(raw[jj].z >> 16));
        acc[6] += a * bf2f((unsigned short)raw[jj].w);
        acc[7] += a * bf2f((unsigned short)(raw[jj].w >> 16));
    }

    float* op = out_f32 + (size_t)node * DIM + c8;
    f32x4 o0, o1;
    o0[0] = fmaxf(bf2f((unsigned short)zr.x) + acc[0], 0.f);
    o0[1] = fmaxf(bf2f((unsigned short)(zr.x >> 16)) + acc[1], 0.f);
    o0[2] = fmaxf(bf2f((unsigned short)zr.y) + acc[2], 0.f);
    o0[3] = fmaxf(bf2f((unsigned short)(zr.y >> 16)) + acc[3], 0.f);
    o1[0] = fmaxf(bf2f((unsigned short)zr.z) + acc[4], 0.f);
    o1[1] = fmaxf(bf2f((unsigned short)(zr.z >> 16)) + acc[5], 0.f);
    o1[2] = fmaxf(bf2f((unsigned short)zr.w) + acc[6], 0.f);
    o1[3] = fmaxf(bf2f((unsigned short)(zr.w >> 16)) + acc[7], 0.f);
    __builtin_nontemporal_store(o0, (f32x4*)op);
    __builtin_nontemporal_store(o1, (f32x4*)(op + 4));
}

// ---------------------------------------------------------------------------
extern "C" void kernel_launch(void* const* d_in, const int* in_sizes, int n_in,
                              void* d_out, int out_size, void* d_ws, size_t ws_size,
                              hipStream_t stream) {
    const float* attr     = (const float*)d_in[0];
    const float* edge_d   = (const float*)d_in[1];
    const float* W_V1     = (const float*)d_in[2];
    const float* W_W1     = (const float*)d_in[3];
    const float* W_U1     = (const float*)d_in[4];
    const float* W_a1     = (const float*)d_in[5];
    const float* W_V2     = (const float*)d_in[6];
    const float* W_W2     = (const float*)d_in[7];
    const float* W_U2     = (const float*)d_in[8];
    const float* W_a2     = (const float*)d_in[9];
    const int*   edge_src = (const int*)d_in[10];

    float* out = (float*)d_out;

    char* ws = (char*)d_ws;
    unsigned short* attrb = (unsigned short*)ws;                       // 26 MB (NPAD rows)
    unsigned short* z1    = (unsigned short*)(ws + 26u * 1024 * 1024); // 26 MB
    unsigned short* zi1   = (unsigned short*)(ws + 52u * 1024 * 1024); // 26 MB
    unsigned short* zi2   = (unsigned short*)(ws + 78u * 1024 * 1024); // 26 MB
    unsigned short* Wc1   = (unsigned short*)(ws + 104u * 1024 * 1024);
    unsigned short* Wc2   = (unsigned short*)(ws + 105u * 1024 * 1024);
    float* s_src0         = (float*)(ws + 106u * 1024 * 1024);
    float* s_src1         = (float*)(ws + 107u * 1024 * 1024);
    float* s_dst0         = (float*)(ws + 108u * 1024 * 1024);
    float* s_dst1         = (float*)(ws + 109u * 1024 * 1024);
    float* t_src0         = (float*)(ws + 110u * 1024 * 1024);
    float* t_src1         = (float*)(ws + 111u * 1024 * 1024);
    float* t_dst0         = (float*)(ws + 112u * 1024 * 1024);
    float* t_dst1         = (float*)(ws + 113u * 1024 * 1024);
    // z2 overlays attrb: attrb is dead after dense_g (layer 1)
    unsigned short* z2    = attrb;

    prep_all<<<6285, 256, 0, stream>>>(attr, W_W1, W_U1, W_W2, W_U2,
                                       attrb, Wc1, Wc2);

    dense_g<<<DGRID, 256, 0, stream>>>(attrb, Wc1, W_a1, z1, zi1,
                                       s_src0, s_src1, s_dst0, s_dst1);

    aggr_dense<<<6250, 256, 0, stream>>>(z1, zi1, s_src0, s_src1, s_dst0, s_dst1,
                                         edge_d, edge_src, W_V1, W_a1,
                                         Wc2, W_a2, z2, zi2,
                                         t_src0, t_src1, t_dst0, t_dst1);

    aggr_final<<<6250, 256, 0, stream>>>(z2, zi2, t_src0, t_src1, t_dst0, t_dst1,
                                         edge_d, edge_src, W_V2, W_a2, out);
}

// Round 9
// 320.907 us; speedup vs baseline: 1.2766x; 1.0031x over previous
//
#include <hip/hip_runtime.h>

#define N_NODES 100000
#define NPAD 100032
#define DEG 16
#define DIM 128
#define E_EDGES 1600000
#define NTILES 1563          // ceil(100000/64)
#define DGRID (196 * 4 * 8)  // 6272 XCD-swizzled (tile, col-block) blocks
#define LSTR 136             // LDS row stride in shorts (16B-aligned, conflict-light)
#define ASTR 17              // LDS per-node stripe stride (16+1, conflict-free)

typedef short bf16x8 __attribute__((ext_vector_type(8)));
typedef float f32x4 __attribute__((ext_vector_type(4)));

__device__ __forceinline__ unsigned short f2bf(float f) {
    unsigned int u = __builtin_bit_cast(unsigned int, f);
    u = (u + 0x7fffu + ((u >> 16) & 1u)) >> 16;
    return (unsigned short)u;
}
__device__ __forceinline__ float bf2f(unsigned short h) {
    unsigned int u = ((unsigned int)h) << 16;
    return __builtin_bit_cast(float, u);
}
__device__ __forceinline__ bf16x8 pack_bf16x8(float4 lo, float4 hi) {
    bf16x8 f;
    f[0] = (short)f2bf(lo.x); f[1] = (short)f2bf(lo.y);
    f[2] = (short)f2bf(lo.z); f[3] = (short)f2bf(lo.w);
    f[4] = (short)f2bf(hi.x); f[5] = (short)f2bf(hi.y);
    f[6] = (short)f2bf(hi.z); f[7] = (short)f2bf(hi.w);
    return f;
}

// ---------------------------------------------------------------------------
// prep_all: attr f32 -> attrb bf16 (pad rows zeroed), W casts, score zeroing.
//   blocks [0, 6252)      : attr cast (8 elems/thread)
//   blocks [6252, 6284)   : W_W1|W_U1 -> Wc1, W_W2|W_U2 -> Wc2
//   block  6284           : zero attrb pad rows 100000..100031
//   blocks [6285, 6481)   : zero s_srcM/s_dstM/t_srcM/t_dstM (49 blocks each)
// ---------------------------------------------------------------------------
__global__ __launch_bounds__(256) void prep_all(
    const float* __restrict__ attr,
    const float* __restrict__ W_W1, const float* __restrict__ W_U1,
    const float* __restrict__ W_W2, const float* __restrict__ W_U2,
    unsigned short* __restrict__ attrb,
    unsigned short* __restrict__ Wc1, unsigned short* __restrict__ Wc2,
    float* __restrict__ s_srcM, float* __restrict__ s_dstM,
    float* __restrict__ t_srcM, float* __restrict__ t_dstM)
{
    const int b = blockIdx.x;
    const int t = threadIdx.x;
    if (b < 6252) {
        size_t g = (size_t)b * 2048 + (size_t)t * 8;
        float4 v0 = make_float4(0.f, 0.f, 0.f, 0.f);
        float4 v1 = v0;
        if (g < (size_t)N_NODES * DIM) {                 // 12.8M % 8 == 0: all-or-none
            v0 = *(const float4*)(attr + g);
            v1 = *(const float4*)(attr + g + 4);
        }
        *(bf16x8*)(attrb + g) = pack_bf16x8(v0, v1);
    } else if (b < 6284) {
        int g = (b - 6252) * 2048 + t * 8;               // 0..65535
        int half = g & 32767;
        const float* src = (g < 32768)
            ? (half < 16384 ? W_W1 + half : W_U1 + (half - 16384))
            : (half < 16384 ? W_W2 + half : W_U2 + (half - 16384));
        unsigned short* dst = (g < 32768) ? Wc1 + half : Wc2 + half;
        float4 v0 = *(const float4*)(src);
        float4 v1 = *(const float4*)(src + 4);
        *(bf16x8*)(dst) = pack_bf16x8(v0, v1);
    } else if (b == 6284) {
        unsigned short* p = attrb + (size_t)N_NODES * DIM; // 32 rows * 128 shorts
        *(uint4*)(p + t * 16) = make_uint4(0, 0, 0, 0);
        *(uint4*)(p + t * 16 + 8) = make_uint4(0, 0, 0, 0);
    } else {
        int k = b - 6285;                                // 0..195
        int arr = k / 49, blk = k % 49;
        float* base = (arr == 0) ? s_srcM : (arr == 1) ? s_dstM
                    : (arr == 2) ? t_srcM : t_dstM;
        int g = blk * 2048 + t * 8;                      // floats; 100000 % 8 == 0
        if (g < N_NODES) {
            *(uint4*)(base + g) = make_uint4(0, 0, 0, 0);
            *(uint4*)(base + g + 4) = make_uint4(0, 0, 0, 0);
        }
    }
}

// ---------------------------------------------------------------------------
// dense_g (r7/r8, validated): z = h @ W_W^T, zi = h @ W_U^T + score partials.
// W slice in LDS (17.4 KB only); H fragments straight from global, issued
// before the W stage. XCD-swizzled. Epilogue now atomicAdds the two cb-block
// partials into MERGED score arrays (2 commutative f32 adds -> bit-exact),
// so the aggr kernel needs only ONE scattered load per edge.
// ---------------------------------------------------------------------------
__global__ __launch_bounds__(256) void dense_g(
    const unsigned short* __restrict__ hsrc, // NPAD x 128 bf16 (pad rows zero)
    const unsigned short* __restrict__ Wc,   // 256 x 128 bf16 (W_W|W_U)
    const float* __restrict__ W_a,           // 257 f32
    unsigned short* __restrict__ z,
    unsigned short* __restrict__ zi,
    float* __restrict__ s_srcM, float* __restrict__ s_dstM)
{
    __shared__ unsigned short Wt[64 * LSTR];

    const int bid = blockIdx.x;
    const int xcd = bid & 7;
    const int q = bid >> 3;
    const int cb = q & 3;                    // col-block 0..3
    const int tile = (q >> 2) * 8 + xcd;
    if (tile >= NTILES) return;
    const int nodebase = tile * 64;
    const int t = threadIdx.x;
    const int wave = t >> 6;
    const int lane = t & 63;
    const int n16 = lane & 15;
    const int quad = lane >> 4;
    const int node = nodebase + wave * 16 + n16;

    // H fragment loads first (latency hides under W stage + barrier)
    bf16x8 hfrag[4];
    const unsigned short* hrow = hsrc + (size_t)node * DIM + quad * 8;
#pragma unroll
    for (int ks = 0; ks < 4; ks++)
        hfrag[ks] = *(const bf16x8*)(hrow + ks * 32);

    // stage W slice into LDS
    {
        int r = t >> 2, c0 = (t & 3) * 32;
        const unsigned short* src = Wc + (size_t)(cb * 64 + r) * DIM + c0;
        unsigned short* dst = Wt + r * LSTR + c0;
#pragma unroll
        for (int i = 0; i < 4; i++)
            *(uint4*)(dst + i * 8) = *(const uint4*)(src + i * 8);
    }
    __syncthreads();

    f32x4 acc[4];
#pragma unroll
    for (int ct = 0; ct < 4; ct++) {
        const unsigned short* wrow = Wt + (ct * 16 + n16) * LSTR + quad * 8;
        f32x4 a = {0.f, 0.f, 0.f, 0.f};
#pragma unroll
        for (int ks = 0; ks < 4; ks++)
            a = __builtin_amdgcn_mfma_f32_16x16x32_bf16(
                    *(const bf16x8*)(wrow + ks * 32), hfrag[ks], a, 0, 0, 0);
        acc[ct] = a;
    }

    if (node < N_NODES) {
        unsigned short* zout = (cb < 2 ? z : zi);
        unsigned short* orow = zout + (size_t)node * DIM + (cb & 1) * 64 + quad * 4;
#pragma unroll
        for (int ct = 0; ct < 4; ct++) {
            uint2 pk;
            pk.x = (unsigned int)f2bf(acc[ct][0]) | ((unsigned int)f2bf(acc[ct][1]) << 16);
            pk.y = (unsigned int)f2bf(acc[ct][2]) | ((unsigned int)f2bf(acc[ct][3]) << 16);
            *(uint2*)(orow + ct * 16) = pk;
        }
    }

    if (cb < 2) {
        float ps = 0.f, pd = 0.f;
#pragma unroll
        for (int ct = 0; ct < 4; ct++) {
            float4 as = *(const float4*)(W_a + cb * 64 + ct * 16 + quad * 4);
            float4 ad = *(const float4*)(W_a + DIM + cb * 64 + ct * 16 + quad * 4);
            ps += acc[ct][0] * as.x + acc[ct][1] * as.y
                + acc[ct][2] * as.z + acc[ct][3] * as.w;
            pd += acc[ct][0] * ad.x + acc[ct][1] * ad.y
                + acc[ct][2] * ad.z + acc[ct][3] * ad.w;
        }
        ps += __shfl_xor(ps, 16); ps += __shfl_xor(ps, 32);
        pd += __shfl_xor(pd, 16); pd += __shfl_xor(pd, 32);
        if (lane < 16 && node < N_NODES) {
            atomicAdd(&s_srcM[node], ps);
            atomicAdd(&s_dstM[node], pd);
        }
    }
}

// ---------------------------------------------------------------------------
// aggr_fused: 16 nodes/block.
//   phase 0: 256 threads stage (src, edge_d) coalesced into LDS.
//   phase 1: 16 threads (one per NODE) each issue 16 scattered score loads
//            at once (16-deep MLP vs alpha_k's 2), compute exp WITHOUT max
//            subtraction (scores are O(1); exp(x)/sum == exp(x-m)/sum' to
//            ~1 ulp, far under the 0.0078 bf16 tolerance), store raw exps +
//            1/denominator to LDS. No shfl chains, no per-edge score loads.
//   phase 2: verbatim aggr_row gather (validated 69us / 73% occ), weights =
//            raw exps, normalization factored out: acc *= rden at the end.
// ---------------------------------------------------------------------------
__global__ __launch_bounds__(256) void aggr_fused(
    const unsigned short* __restrict__ z,    // z1
    const unsigned short* __restrict__ zi,   // zi1
    const float* __restrict__ s_srcM, const float* __restrict__ s_dstM,
    const float* __restrict__ edge_d,
    const int* __restrict__ edge_src,
    const float* __restrict__ W_V,
    const float* __restrict__ W_a,
    unsigned short* __restrict__ hout)       // NPAD x 128 bf16
{
    __shared__ float ex_s[16 * ASTR];
    __shared__ int   src_s[16 * ASTR];
    __shared__ float ed_s[16 * ASTR];
    __shared__ float rden_s[16];

    const int t = threadIdx.x;
    const int base = blockIdx.x * 16;
    const int nl = t >> 4;
    const int j  = t & 15;

    {
        int e0 = base * DEG + t;             // 256 consecutive edges
        src_s[nl * ASTR + j] = __builtin_nontemporal_load(edge_src + e0);
        ed_s[nl * ASTR + j]  = __builtin_nontemporal_load(edge_d + e0);
    }
    __syncthreads();

    if (t < 16) {
        float coef = W_V[0] * W_a[2 * DIM];
        float sdst = s_dstM[base + t];
        float ssrc[16];
#pragma unroll
        for (int e = 0; e < DEG; e++)
            ssrc[e] = s_srcM[src_s[t * ASTR + e]];   // 16 scattered, all in flight
        float d = 0.f;
#pragma unroll
        for (int e = 0; e < DEG; e++) {
            float x = ssrc[e] + sdst + ed_s[t * ASTR + e] * coef;
            x = x > 0.f ? x : 0.01f * x;
            float ex = __expf(x);
            ex_s[t * ASTR + e] = ex;
            d += ex;
        }
        rden_s[t] = 1.f / d;
    }
    __syncthreads();

    const int node = base + nl;
    const int c8 = j * 8;
    const unsigned short* zc = z + c8;

    float acc[8] = {};
#pragma unroll
    for (int e = 0; e < DEG; e++) {
        int   sj = src_s[nl * ASTR + e];
        float a  = ex_s[nl * ASTR + e];
        uint4 r = *(const uint4*)(zc + (size_t)sj * DIM);
        acc[0] += a * bf2f((unsigned short)(r.x & 0xffff));
        acc[1] += a * bf2f((unsigned short)(r.x >> 16));
        acc[2] += a * bf2f((unsigned short)(r.y & 0xffff));
        acc[3] += a * bf2f((unsigned short)(r.y >> 16));
        acc[4] += a * bf2f((unsigned short)(r.z & 0xffff));
        acc[5] += a * bf2f((unsigned short)(r.z >> 16));
        acc[6] += a * bf2f((unsigned short)(r.w & 0xffff));
        acc[7] += a * bf2f((unsigned short)(r.w >> 16));
    }
    float rd = rden_s[nl];

    uint4 zr = *(const uint4*)(zi + (size_t)node * DIM + c8);
    float v[8];
    v[0] = fmaxf(bf2f((unsigned short)(zr.x & 0xffff)) + acc[0] * rd, 0.f);
    v[1] = fmaxf(bf2f((unsigned short)(zr.x >> 16)) + acc[1] * rd, 0.f);
    v[2] = fmaxf(bf2f((unsigned short)(zr.y & 0xffff)) + acc[2] * rd, 0.f);
    v[3] = fmaxf(bf2f((unsigned short)(zr.y >> 16)) + acc[3] * rd, 0.f);
    v[4] = fmaxf(bf2f((unsigned short)(zr.z & 0xffff)) + acc[4] * rd, 0.f);
    v[5] = fmaxf(bf2f((unsigned short)(zr.z >> 16)) + acc[5] * rd, 0.f);
    v[6] = fmaxf(bf2f((unsigned short)(zr.w & 0xffff)) + acc[6] * rd, 0.f);
    v[7] = fmaxf(bf2f((unsigned short)(zr.w >> 16)) + acc[7] * rd, 0.f);

    uint4 pk;
    pk.x = (unsigned int)f2bf(v[0]) | ((unsigned int)f2bf(v[1]) << 16);
    pk.y = (unsigned int)f2bf(v[2]) | ((unsigned int)f2bf(v[3]) << 16);
    pk.z = (unsigned int)f2bf(v[4]) | ((unsigned int)f2bf(v[5]) << 16);
    pk.w = (unsigned int)f2bf(v[6]) | ((unsigned int)f2bf(v[7]) << 16);
    *(uint4*)(hout + (size_t)node * DIM + c8) = pk;
}

// ---------------------------------------------------------------------------
// aggr_fused_final: same structure, f32 nt output.
// ---------------------------------------------------------------------------
__global__ __launch_bounds__(256) void aggr_fused_final(
    const unsigned short* __restrict__ z,    // z2
    const unsigned short* __restrict__ zi,   // zi2
    const float* __restrict__ s_srcM, const float* __restrict__ s_dstM,
    const float* __restrict__ edge_d,
    const int* __restrict__ edge_src,
    const float* __restrict__ W_V,
    const float* __restrict__ W_a,
    float* __restrict__ out_f32)
{
    __shared__ float ex_s[16 * ASTR];
    __shared__ int   src_s[16 * ASTR];
    __shared__ float ed_s[16 * ASTR];
    __shared__ float rden_s[16];

    const int t = threadIdx.x;
    const int base = blockIdx.x * 16;
    const int nl = t >> 4;
    const int j  = t & 15;

    {
        int e0 = base * DEG + t;
        src_s[nl * ASTR + j] = __builtin_nontemporal_load(edge_src + e0);
        ed_s[nl * ASTR + j]  = __builtin_nontemporal_load(edge_d + e0);
    }
    __syncthreads();

    if (t < 16) {
        float coef = W_V[0] * W_a[2 * DIM];
        float sdst = s_dstM[base + t];
        float ssrc[16];
#pragma unroll
        for (int e = 0; e < DEG; e++)
            ssrc[e] = s_srcM[src_s[t * ASTR + e]];
        float d = 0.f;
#pragma unroll
        for (int e = 0; e < DEG; e++) {
            float x = ssrc[e] + sdst + ed_s[t * ASTR + e] * coef;
            x = x > 0.f ? x : 0.01f * x;
            float ex = __expf(x);
            ex_s[t * ASTR + e] = ex;
            d += ex;
        }
        rden_s[t] = 1.f / d;
    }
    __syncthreads();

    const int node = base + nl;
    const int c8 = j * 8;
    const unsigned short* zc = z + c8;

    float acc[8] = {};
#pragma unroll
    for (int e = 0; e < DEG; e++) {
        int   sj = src_s[nl * ASTR + e];
        float a  = ex_s[nl * ASTR + e];
        uint4 r = *(const uint4*)(zc + (size_t)sj * DIM);
        acc[0] += a * bf2f((unsigned short)(r.x & 0xffff));
        acc[1] += a * bf2f((unsigned short)(r.x >> 16));
        acc[2] += a * bf2f((unsigned short)(r.y & 0xffff));
        acc[3] += a * bf2f((unsigned short)(r.y >> 16));
        acc[4] += a * bf2f((unsigned short)(r.z & 0xffff));
        acc[5] += a * bf2f((unsigned short)(r.z >> 16));
        acc[6] += a * bf2f((unsigned short)(r.w & 0xffff));
        acc[7] += a * bf2f((unsigned short)(r.w >> 16));
    }
    float rd = rden_s[nl];

    uint4 zr = *(const uint4*)(zi + (size_t)node * DIM + c8);
    float* op = out_f32 + (size_t)node * DIM + c8;
    f32x4 o0, o1;
    o0[0] = fmaxf(bf2f((unsigned short)(zr.x & 0xffff)) + acc[0] * rd, 0.f);
    o0[1] = fmaxf(bf2f((unsigned short)(zr.x >> 16)) + acc[1] * rd, 0.f);
    o0[2] = fmaxf(bf2f((unsigned short)(zr.y & 0xffff)) + acc[2] * rd, 0.f);
    o0[3] = fmaxf(bf2f((unsigned short)(zr.y >> 16)) + acc[3] * rd, 0.f);
    o1[0] = fmaxf(bf2f((unsigned short)(zr.z & 0xffff)) + acc[4] * rd, 0.f);
    o1[1] = fmaxf(bf2f((unsigned short)(zr.z >> 16)) + acc[5] * rd, 0.f);
    o1[2] = fmaxf(bf2f((unsigned short)(zr.w & 0xffff)) + acc[6] * rd, 0.f);
    o1[3] = fmaxf(bf2f((unsigned short)(zr.w >> 16)) + acc[7] * rd, 0.f);
    __builtin_nontemporal_store(o0, (f32x4*)op);
    __builtin_nontemporal_store(o1, (f32x4*)(op + 4));
}

// ---------------------------------------------------------------------------
extern "C" void kernel_launch(void* const* d_in, const int* in_sizes, int n_in,
                              void* d_out, int out_size, void* d_ws, size_t ws_size,
                              hipStream_t stream) {
    const float* attr     = (const float*)d_in[0];
    const float* edge_d   = (const float*)d_in[1];
    const float* W_V1     = (const float*)d_in[2];
    const float* W_W1     = (const float*)d_in[3];
    const float* W_U1     = (const float*)d_in[4];
    const float* W_a1     = (const float*)d_in[5];
    const float* W_V2     = (const float*)d_in[6];
    const float* W_W2     = (const float*)d_in[7];
    const float* W_U2     = (const float*)d_in[8];
    const float* W_a2     = (const float*)d_in[9];
    const int*   edge_src = (const int*)d_in[10];

    float* out = (float*)d_out;

    char* ws = (char*)d_ws;
    unsigned short* attrb = (unsigned short*)ws;                       // 26 MB; h1 overlays
    unsigned short* z1    = (unsigned short*)(ws + 26u * 1024 * 1024); // 26 MB; z2 overlays
    unsigned short* zi1   = (unsigned short*)(ws + 52u * 1024 * 1024); // 26 MB; zi2 overlays
    unsigned short* Wc1   = (unsigned short*)(ws + 78u * 1024 * 1024);
    unsigned short* Wc2   = (unsigned short*)(ws + 79u * 1024 * 1024);
    float* s_srcM         = (float*)(ws + 80u * 1024 * 1024);
    float* s_dstM         = (float*)(ws + 81u * 1024 * 1024);
    float* t_srcM         = (float*)(ws + 82u * 1024 * 1024);
    float* t_dstM         = (float*)(ws + 83u * 1024 * 1024);
    // overlays (strictly sequential deps):
    //   h1 <- attrb (attrb dead after dense_g L1; pad rows stay zeroed bf16)
    //   z2 <- z1, zi2 <- zi1 (dead after aggr_fused)
    unsigned short* h1  = attrb;
    unsigned short* z2  = z1;
    unsigned short* zi2 = zi1;

    prep_all<<<6481, 256, 0, stream>>>(attr, W_W1, W_U1, W_W2, W_U2,
                                       attrb, Wc1, Wc2,
                                       s_srcM, s_dstM, t_srcM, t_dstM);

    // ---- layer 1 ----
    dense_g<<<DGRID, 256, 0, stream>>>(attrb, Wc1, W_a1, z1, zi1,
                                       s_srcM, s_dstM);

    aggr_fused<<<6250, 256, 0, stream>>>(z1, zi1, s_srcM, s_dstM,
                                         edge_d, edge_src, W_V1, W_a1, h1);

    // ---- layer 2 ----
    dense_g<<<DGRID, 256, 0, stream>>>(h1, Wc2, W_a2, z2, zi2,
                                       t_srcM, t_dstM);

    aggr_fused_final<<<6250, 256, 0, stream>>>(z2, zi2, t_srcM, t_dstM,
                                               edge_d, edge_src, W_V2, W_a2, out);
}